// Round 5
// baseline (568.768 us; speedup 1.0000x reference)
//
#include <hip/hip_runtime.h>
#include <hip/hip_bf16.h>

#define NROWS 8192

typedef __bf16 bf16x8 __attribute__((ext_vector_type(8)));
typedef float f32x4 __attribute__((ext_vector_type(4)));
typedef int i32x4 __attribute__((ext_vector_type(4)));
typedef unsigned short ushort_t;
typedef unsigned int uint_t;

__device__ __forceinline__ ushort_t f2bf(float f) {
  uint_t u = __builtin_bit_cast(uint_t, f);
  u += 0x7fffu + ((u >> 16) & 1u);   // round-to-nearest-even
  return (ushort_t)(u >> 16);
}
__device__ __forceinline__ float bf2f(ushort_t h) {
  uint_t u = ((uint_t)h) << 16;
  return __builtin_bit_cast(float, u);
}
// pack two f32 -> one dword of 2 bf16 (round-half-up; <=0.5ulp, adj in (0,1])
__device__ __forceinline__ uint_t pack2bf(float lo, float hi) {
  uint_t a = __builtin_bit_cast(uint_t, lo) + 0x8000u;
  uint_t b = __builtin_bit_cast(uint_t, hi) + 0x8000u;
  return __builtin_amdgcn_perm(b, a, 0x07060302u);  // [a.b2,a.b3,b.b2,b.b3]
}

// ---------------------------------------------------------------------------
// lin: gl = relu(x@W1+b1) -> bf16 [N][F]; sq[r] = sum(bf16(gl)^2) fp32;
//      hT = (x@W2+b2)^T ones-padded -> bf16 [F+16][N] (row F = 1.0, rest 0)
// ---------------------------------------------------------------------------
template<int DIN, int F>
__global__ __launch_bounds__(256) void lin_kernel(
    const float* __restrict__ x,
    const float* __restrict__ W1, const float* __restrict__ b1,
    const float* __restrict__ W2, const float* __restrict__ b2,
    ushort_t* __restrict__ gl, float* __restrict__ sq, ushort_t* __restrict__ hT)
{
  constexpr int ROWS = 16;
  constexpr int RP   = 256 / F;      // row phases handled in parallel
  constexpr int RPT  = ROWS / RP;    // rows per thread
  __shared__ float xs[ROWS][DIN];
  __shared__ float hs[ROWS][F];
  __shared__ float sqs[ROWS];
  const int t  = threadIdx.x;
  const int r0 = blockIdx.x * ROWS;

  for (int i = t; i < ROWS * DIN; i += 256)
    xs[i / DIN][i % DIN] = x[(size_t)(r0 + i / DIN) * DIN + (i % DIN)];
  if (t < ROWS) sqs[t] = 0.f;
  __syncthreads();

  const int c = t % F, rr = t / F;
  float a1[RPT], a2[RPT];
  for (int i = 0; i < RPT; ++i) { a1[i] = b1[c]; a2[i] = b2[c]; }
  for (int k = 0; k < DIN; ++k) {
    float w1 = W1[(size_t)k * F + c];
    float w2 = W2[(size_t)k * F + c];
#pragma unroll
    for (int i = 0; i < RPT; ++i) {
      float xv = xs[rr + i * RP][k];
      a1[i] = fmaf(xv, w1, a1[i]);
      a2[i] = fmaf(xv, w2, a2[i]);
    }
  }
#pragma unroll
  for (int i = 0; i < RPT; ++i) {
    int r = rr + i * RP;
    float g = fmaxf(a1[i], 0.f);
    ushort_t gb = f2bf(g);
    gl[(size_t)(r0 + r) * F + c] = gb;
    float gf = bf2f(gb);
    atomicAdd(&sqs[r], gf * gf);
    hs[r][c] = a2[i];
  }
  __syncthreads();
  if (t < ROWS) sq[r0 + t] = sqs[t];
  if (t < F + 16) {
    ushort_t tmp[ROWS];
    if (t < F) {
#pragma unroll
      for (int r = 0; r < ROWS; ++r) tmp[r] = f2bf(hs[r][t]);
    } else {
      ushort_t v = (t == F) ? (ushort_t)0x3F80 : (ushort_t)0;  // bf16(1.0)
#pragma unroll
      for (int r = 0; r < ROWS; ++r) tmp[r] = v;
    }
    uint4* dst = (uint4*)(hT + (size_t)t * NROWS + r0);
    dst[0] = ((const uint4*)tmp)[0];
    dst[1] = ((const uint4*)tmp)[1];
  }
}

// ---------------------------------------------------------------------------
// fused (R5): NO LDS, NO fences, NO syncthreads. Swapped phase A:
//   S^T = mfma(A=gl_j, B=gl_i) -> D: i=lane&15(col), j=4*(lane>>4)+reg(row)
// adj computed in-register; the 4-element k-groups are rotated into the
// phase-B A-fragment layout (k=8*(lane>>4)+e) with 16 ds_bpermute + 8 selects
// per iter. Phase B: acc += mfma(adjFrag, hT_frag) over two K=32 windows.
// Whole j-loop is a barrier-free DAG -> compiler pipelines across iters.
// ---------------------------------------------------------------------------
template<int F>
__global__ __launch_bounds__(256) void fused_kernel(
    const ushort_t* __restrict__ gl, const float* __restrict__ sq,
    const ushort_t* __restrict__ hT,
    const float* __restrict__ temp_p, const float* __restrict__ theta_p,
    float* __restrict__ partial)
{
  constexpr int Fp  = F + 16;
  constexpr int NT  = Fp / 16;    // 9 (F=128) or 5 (F=64)
  constexpr int KK  = F / 32;     // 4 or 2
  constexpr int JS  = 8;
  constexpr int JCH = NROWS / JS; // 1024 j-rows per block
  constexpr float EPS = 1.1920929e-07f;

  const int w = threadIdx.x >> 6, lane = threadIdx.x & 63;
  const int g = lane >> 4, q = lane & 15;
  const int irow  = blockIdx.x * 64 + 16 * w;   // this wave's private 16 rows
  const int jbase = blockIdx.y * JCH;
  const float c1 = 1.0f + *temp_p;
  const float c0 = 5.0f + *theta_p;

  // bpermute byte-indices for the k-group rotation (hoisted):
  // target lane pulls from lane q+32*(g&1) (l0) and that +16 (l1)
  const int l0 = (((lane & 15) | ((lane & 16) << 1)) << 2);
  const int l1 = l0 + 64;
  const bool hsel = (lane & 32) != 0;   // g>=2 -> take tt-odd data

  // hoist i-side B-fragments and sq_i (one scalar per lane: i = irow+q)
  bf16x8 iF[KK];
#pragma unroll
  for (int kk = 0; kk < KK; ++kk)
    iF[kk] = *(const bf16x8*)(gl + (size_t)(irow + q) * F + 32 * kk + 8 * g);
  const float sqi = sq[irow + q];

  f32x4 acc[NT];
#pragma unroll
  for (int i = 0; i < NT; ++i) acc[i] = (f32x4){0.f, 0.f, 0.f, 0.f};

  for (int j0 = jbase; j0 < jbase + JCH; j0 += 64) {
    // ---- phase A (swapped): S^T tiles; lane holds i=q col, j=16tt+4g+r rows
    f32x4 s[4], sqjv[4];
#pragma unroll
    for (int tt = 0; tt < 4; ++tt) {
      sqjv[tt] = *(const f32x4*)(sq + j0 + 16 * tt + 4 * g);
      f32x4 cacc = (f32x4){0.f, 0.f, 0.f, 0.f};
#pragma unroll
      for (int kk = 0; kk < KK; ++kk) {
        bf16x8 jF = *(const bf16x8*)(gl + (size_t)(j0 + 16 * tt + q) * F + 32 * kk + 8 * g);
        cacc = __builtin_amdgcn_mfma_f32_16x16x32_bf16(jF, iF[kk], cacc, 0, 0, 0);
      }
      s[tt] = cacc;
    }
    // ---- elementwise: adj = sigmoid(c1*dist+c0), packed 2-per-dword
    uint_t pk[4][2];
#pragma unroll
    for (int tt = 0; tt < 4; ++tt) {
#pragma unroll
      for (int rp = 0; rp < 2; ++rp) {
        float av[2];
#pragma unroll
        for (int e = 0; e < 2; ++e) {
          int r = 2 * rp + e;
          float t1 = sqi + sqjv[tt][r];
          float diff = fmaxf(fmaf(-2.f, s[tt][r], t1), 0.f);
          float arg = c0;
          if (diff != 0.f) arg = c0 - c1 * __builtin_amdgcn_sqrtf(diff + EPS);
          av[e] = __builtin_amdgcn_rcpf(1.f + __expf(-arg));
        }
        pk[tt][rp] = pack2bf(av[0], av[1]);
      }
    }
    // ---- phase B: two K=32 windows (tt pairs); A-frag via bpermute rotation
#pragma unroll
    for (int P = 0; P < 2; ++P) {
      int a0 = (int)pk[2 * P][0],     a1 = (int)pk[2 * P][1];
      int b0 = (int)pk[2 * P + 1][0], b1 = (int)pk[2 * P + 1][1];
      int pa0 = __builtin_amdgcn_ds_bpermute(l0, a0);
      int pb0 = __builtin_amdgcn_ds_bpermute(l0, b0);
      int pa1 = __builtin_amdgcn_ds_bpermute(l0, a1);
      int pb1 = __builtin_amdgcn_ds_bpermute(l0, b1);
      int pa2 = __builtin_amdgcn_ds_bpermute(l1, a0);
      int pb2 = __builtin_amdgcn_ds_bpermute(l1, b0);
      int pa3 = __builtin_amdgcn_ds_bpermute(l1, a1);
      int pb3 = __builtin_amdgcn_ds_bpermute(l1, b1);
      i32x4 dw;
      dw[0] = hsel ? pb0 : pa0;
      dw[1] = hsel ? pb1 : pa1;
      dw[2] = hsel ? pb2 : pa2;
      dw[3] = hsel ? pb3 : pa3;
      bf16x8 adjF = __builtin_bit_cast(bf16x8, dw);
#pragma unroll
      for (int t2 = 0; t2 < NT; ++t2) {
        bf16x8 hF = *(const bf16x8*)(hT + (size_t)(16 * t2 + q) * NROWS + j0 + 32 * P + 8 * g);
        acc[t2] = __builtin_amdgcn_mfma_f32_16x16x32_bf16(adjF, hF, acc[t2], 0, 0, 0);
      }
    }
  }

  // ---- epilogue: wave owns rows irow..irow+15 -> direct disjoint store
  float* op = partial + ((size_t)blockIdx.y * NROWS + irow) * Fp;
#pragma unroll
  for (int t2 = 0; t2 < NT; ++t2)
#pragma unroll
    for (int r = 0; r < 4; ++r)
      op[(size_t)(4 * g + r) * Fp + 16 * t2 + q] = acc[t2][r];
}

// x_next = relu(sum_js(partial col c) / sum_js(partial col F))
template<int F, bool RELU>
__global__ __launch_bounds__(256) void reduce_div_kernel(
    const float* __restrict__ partial, float* __restrict__ out)
{
  int idx = blockIdx.x * 256 + threadIdx.x;
  int r = idx / F, c = idx % F;
  size_t base = (size_t)r * (F + 16);
  size_t stride = (size_t)NROWS * (F + 16);
  float s = 0.f, d = 0.f;
#pragma unroll
  for (int js = 0; js < 8; ++js) {
    s += partial[js * stride + base + c];
    d += partial[js * stride + base + F];
  }
  float v = s / d;
  if (RELU) v = fmaxf(v, 0.f);
  out[idx] = v;
}

// out = softmax(sum_js(partial)/deg) rowwise; one wave per row
__global__ __launch_bounds__(64) void reduce_softmax_kernel(
    const float* __restrict__ partial, float* __restrict__ out)
{
  int r = blockIdx.x, c = threadIdx.x;
  size_t base = (size_t)r * 80;
  size_t stride = (size_t)NROWS * 80;
  float v = 0.f, d = 0.f;
#pragma unroll
  for (int js = 0; js < 8; ++js) {
    v += partial[js * stride + base + c];
    d += partial[js * stride + base + 64];
  }
  v /= d;
  float m = v;
  for (int o = 32; o > 0; o >>= 1) m = fmaxf(m, __shfl_xor(m, o, 64));
  float e = __expf(v - m);
  float s = e;
  for (int o = 32; o > 0; o >>= 1) s += __shfl_xor(s, o, 64);
  out[(size_t)r * 64 + c] = e / s;
}

extern "C" void kernel_launch(void* const* d_in, const int* in_sizes, int n_in,
                              void* d_out, int out_size, void* d_ws, size_t ws_size,
                              hipStream_t stream) {
  const float* feat  = (const float*)d_in[0];
  const float* Wgl0  = (const float*)d_in[6];
  const float* bgl0  = (const float*)d_in[7];
  const float* Wgnn0 = (const float*)d_in[8];
  const float* bgnn0 = (const float*)d_in[9];
  const float* Wgl1  = (const float*)d_in[10];
  const float* bgl1  = (const float*)d_in[11];
  const float* Wgnn1 = (const float*)d_in[12];
  const float* bgnn1 = (const float*)d_in[13];
  const float* temp  = (const float*)d_in[14];
  const float* theta = (const float*)d_in[15];
  float* out = (float*)d_out;

  char* ws = (char*)d_ws;
  size_t off = 0;
  auto alloc = [&](size_t bytes) {
    char* p = ws + off;
    off = (off + bytes + 255) & ~(size_t)255;
    return p;
  };
  float*    par0 = (float*)alloc(8ull * NROWS * 144 * 4);  // 37.7 MB
  float*    par1 = par0;  // aliased: par0 is consumed before fused<64> runs
  float*    x1   = (float*)alloc(8192ull * 128 * 4);
  ushort_t* gl0  = (ushort_t*)alloc(8192ull * 128 * 2);
  ushort_t* gl1  = (ushort_t*)alloc(8192ull * 64 * 2);
  ushort_t* h0T  = (ushort_t*)alloc(144ull * 8192 * 2);
  ushort_t* h1T  = (ushort_t*)alloc(80ull * 8192 * 2);
  float*    sq0  = (float*)alloc(8192ull * 4);
  float*    sq1  = (float*)alloc(8192ull * 4);

  lin_kernel<256, 128><<<512, 256, 0, stream>>>(feat, Wgl0, bgl0, Wgnn0, bgnn0, gl0, sq0, h0T);
  fused_kernel<128><<<dim3(128, 8), 256, 0, stream>>>(gl0, sq0, h0T, temp, theta, par0);
  reduce_div_kernel<128, true><<<(8192 * 128) / 256, 256, 0, stream>>>(par0, x1);

  lin_kernel<128, 64><<<512, 256, 0, stream>>>(x1, Wgl1, bgl1, Wgnn1, bgnn1, gl1, sq1, h1T);
  fused_kernel<64><<<dim3(128, 8), 256, 0, stream>>>(gl1, sq1, h1T, temp, theta, par1);
  reduce_softmax_kernel<<<8192, 64, 0, stream>>>(par1, out);
}

// Round 6
// 535.872 us; speedup vs baseline: 1.0614x; 1.0614x over previous
//
#include <hip/hip_runtime.h>
#include <hip/hip_bf16.h>

#define NROWS 8192

typedef __bf16 bf16x8 __attribute__((ext_vector_type(8)));
typedef float f32x4 __attribute__((ext_vector_type(4)));
typedef unsigned short ushort_t;
typedef unsigned int uint_t;

__device__ __forceinline__ ushort_t f2bf(float f) {
  uint_t u = __builtin_bit_cast(uint_t, f);
  u += 0x7fffu + ((u >> 16) & 1u);   // round-to-nearest-even
  return (ushort_t)(u >> 16);
}
__device__ __forceinline__ float bf2f(ushort_t h) {
  uint_t u = ((uint_t)h) << 16;
  return __builtin_bit_cast(float, u);
}

// ---------------------------------------------------------------------------
// lin: gl = relu(x@W1+b1) -> bf16 [N][F]; sq[r] = sum(bf16(gl)^2) fp32;
//      hT = (x@W2+b2)^T ones-padded -> bf16 [F+16][N] (row F = 1.0, rest 0)
// ---------------------------------------------------------------------------
template<int DIN, int F>
__global__ __launch_bounds__(256) void lin_kernel(
    const float* __restrict__ x,
    const float* __restrict__ W1, const float* __restrict__ b1,
    const float* __restrict__ W2, const float* __restrict__ b2,
    ushort_t* __restrict__ gl, float* __restrict__ sq, ushort_t* __restrict__ hT)
{
  constexpr int ROWS = 16;
  constexpr int RP   = 256 / F;      // row phases handled in parallel
  constexpr int RPT  = ROWS / RP;    // rows per thread
  __shared__ float xs[ROWS][DIN];
  __shared__ float hs[ROWS][F];
  __shared__ float sqs[ROWS];
  const int t  = threadIdx.x;
  const int r0 = blockIdx.x * ROWS;

  for (int i = t; i < ROWS * DIN; i += 256)
    xs[i / DIN][i % DIN] = x[(size_t)(r0 + i / DIN) * DIN + (i % DIN)];
  if (t < ROWS) sqs[t] = 0.f;
  __syncthreads();

  const int c = t % F, rr = t / F;
  float a1[RPT], a2[RPT];
  for (int i = 0; i < RPT; ++i) { a1[i] = b1[c]; a2[i] = b2[c]; }
  for (int k = 0; k < DIN; ++k) {
    float w1 = W1[(size_t)k * F + c];
    float w2 = W2[(size_t)k * F + c];
#pragma unroll
    for (int i = 0; i < RPT; ++i) {
      float xv = xs[rr + i * RP][k];
      a1[i] = fmaf(xv, w1, a1[i]);
      a2[i] = fmaf(xv, w2, a2[i]);
    }
  }
#pragma unroll
  for (int i = 0; i < RPT; ++i) {
    int r = rr + i * RP;
    float g = fmaxf(a1[i], 0.f);
    ushort_t gb = f2bf(g);
    gl[(size_t)(r0 + r) * F + c] = gb;
    float gf = bf2f(gb);
    atomicAdd(&sqs[r], gf * gf);
    hs[r][c] = a2[i];
  }
  __syncthreads();
  if (t < ROWS) sq[r0 + t] = sqs[t];
  if (t < F + 16) {
    ushort_t tmp[ROWS];
    if (t < F) {
#pragma unroll
      for (int r = 0; r < ROWS; ++r) tmp[r] = f2bf(hs[r][t]);
    } else {
      ushort_t v = (t == F) ? (ushort_t)0x3F80 : (ushort_t)0;  // bf16(1.0)
#pragma unroll
      for (int r = 0; r < ROWS; ++r) tmp[r] = v;
    }
    uint4* dst = (uint4*)(hT + (size_t)t * NROWS + r0);
    dst[0] = ((const uint4*)tmp)[0];
    dst[1] = ((const uint4*)tmp)[1];
  }
}

// ---------------------------------------------------------------------------
// fused (R6 = R4 + pragma unroll 1): block = 4 waves = one 64-row i-tile,
// each wave privately owns a 16-row strip. Per 64-col j-tile: S = gl_i@gl_j^T
// (MFMA) -> adj = sigmoid((1+temp)*dist+5+theta) -> bf16 via swizzled
// wave-private LDS -> acc += adj @ h (ones col = deg). j-split JS=8 across
// blocks; disjoint partial stores, no atomics.
// R6 theory: previous rounds fully unrolled the 8-32-iter j-loop ->
// 50-100KB body >> 32KB L1I -> I-cache thrash = the ~10x issue-util gap.
// Keep the body to ONE iteration (~3.5KB).
// ---------------------------------------------------------------------------
template<int F>
__global__ __launch_bounds__(256) void fused_kernel(
    const ushort_t* __restrict__ gl, const float* __restrict__ sq,
    const ushort_t* __restrict__ hT,
    const float* __restrict__ temp_p, const float* __restrict__ theta_p,
    float* __restrict__ partial)
{
  constexpr int Fp  = F + 16;
  constexpr int NT  = Fp / 16;    // 9 (F=128) or 5 (F=64)
  constexpr int KK  = F / 32;     // 4 or 2
  constexpr int JS  = 8;
  constexpr int JCH = NROWS / JS; // 1024 j-rows per block
  constexpr float EPS = 1.1920929e-07f;
  __shared__ __align__(16) ushort_t adjlds[64 * 64];  // 8 KB, XOR-swizzled

  const int w = threadIdx.x >> 6, lane = threadIdx.x & 63;
  const int g = lane >> 4, q = lane & 15;
  const int irow  = blockIdx.x * 64 + 16 * w;   // this wave's private 16 rows
  const int jbase = blockIdx.y * JCH;
  const float c1 = 1.0f + *temp_p;
  const float c0 = 5.0f + *theta_p;

  // hoist A-fragments (gl_i) and sq_i for the whole j-loop
  bf16x8 aF[KK];
#pragma unroll
  for (int kk = 0; kk < KK; ++kk)
    aF[kk] = *(const bf16x8*)(gl + (size_t)(irow + q) * F + 32 * kk + 8 * g);
  float sqi[4];
#pragma unroll
  for (int r = 0; r < 4; ++r) sqi[r] = sq[irow + 4 * g + r];

  f32x4 acc[NT];
#pragma unroll
  for (int i = 0; i < NT; ++i) acc[i] = (f32x4){0.f, 0.f, 0.f, 0.f};

#pragma unroll 1   // CRITICAL: keep body within L1I (R6 theory)
  for (int j0 = jbase; j0 < jbase + JCH; j0 += 64) {
    // ---- phase A: S tile [16][64]
    f32x4 s[4];
    float sqj[4];
#pragma unroll
    for (int tt = 0; tt < 4; ++tt) {
      sqj[tt] = sq[j0 + 16 * tt + q];
      f32x4 cacc = (f32x4){0.f, 0.f, 0.f, 0.f};
#pragma unroll
      for (int kk = 0; kk < KK; ++kk) {
        bf16x8 b = *(const bf16x8*)(gl + (size_t)(j0 + 16 * tt + q) * F + 32 * kk + 8 * g);
        cacc = __builtin_amdgcn_mfma_f32_16x16x32_bf16(aF[kk], b, cacc, 0, 0, 0);
      }
      s[tt] = cacc;
    }
    // ---- elementwise: diff -> dist -> sigmoid -> bf16 adj into LDS
#pragma unroll
    for (int tt = 0; tt < 4; ++tt) {
#pragma unroll
      for (int r = 0; r < 4; ++r) {
        float diff = fmaxf(sqi[r] + sqj[tt] - 2.f * s[tt][r], 0.f);
        float arg = c0;
        if (diff != 0.f) arg = c0 - c1 * __builtin_amdgcn_sqrtf(diff + EPS);
        float adjv = __builtin_amdgcn_rcpf(1.f + __expf(-arg));
        int row = 16 * w + 4 * g + r;
        int col = 16 * tt + q;
        int byte = row * 128 + ((col * 2) ^ ((row & 7) << 4));
        *(ushort_t*)((char*)adjlds + byte) = f2bf(adjv);
      }
    }
    // RAW fence (cross-lane, same wave): writes visible before reads.
    asm volatile("s_waitcnt lgkmcnt(0)" ::: "memory");
    // ---- phase B: acc += adj[16][64] @ h[64][Fp]
#pragma unroll
    for (int kk2 = 0; kk2 < 2; ++kk2) {
      int row = 16 * w + q;
      int byte = row * 128 + ((64 * kk2 + 16 * g) ^ ((row & 7) << 4));
      bf16x8 aP = *(const bf16x8*)((char*)adjlds + byte);
#pragma unroll
      for (int t2 = 0; t2 < NT; ++t2) {
        bf16x8 b = *(const bf16x8*)(hT + (size_t)(16 * t2 + q) * NROWS + j0 + 32 * kk2 + 8 * g);
        acc[t2] = __builtin_amdgcn_mfma_f32_16x16x32_bf16(aP, b, acc[t2], 0, 0, 0);
      }
    }
    // WAR fence: this iter's ds_reads done before next iter's ds_writes.
    asm volatile("s_waitcnt lgkmcnt(0)" ::: "memory");
  }

  // ---- epilogue: each wave owns rows irow..irow+15 -> direct disjoint store
  float* op = partial + ((size_t)blockIdx.y * NROWS + irow) * Fp;
#pragma unroll
  for (int t2 = 0; t2 < NT; ++t2)
#pragma unroll
    for (int r = 0; r < 4; ++r)
      op[(size_t)(4 * g + r) * Fp + 16 * t2 + q] = acc[t2][r];
}

// x_next = relu(sum_js(partial col c) / sum_js(partial col F))
template<int F, bool RELU>
__global__ __launch_bounds__(256) void reduce_div_kernel(
    const float* __restrict__ partial, float* __restrict__ out)
{
  int idx = blockIdx.x * 256 + threadIdx.x;
  int r = idx / F, c = idx % F;
  size_t base = (size_t)r * (F + 16);
  size_t stride = (size_t)NROWS * (F + 16);
  float s = 0.f, d = 0.f;
#pragma unroll
  for (int js = 0; js < 8; ++js) {
    s += partial[js * stride + base + c];
    d += partial[js * stride + base + F];
  }
  float v = s / d;
  if (RELU) v = fmaxf(v, 0.f);
  out[idx] = v;
}

// out = softmax(sum_js(partial)/deg) rowwise; one wave per row
__global__ __launch_bounds__(64) void reduce_softmax_kernel(
    const float* __restrict__ partial, float* __restrict__ out)
{
  int r = blockIdx.x, c = threadIdx.x;
  size_t base = (size_t)r * 80;
  size_t stride = (size_t)NROWS * 80;
  float v = 0.f, d = 0.f;
#pragma unroll
  for (int js = 0; js < 8; ++js) {
    v += partial[js * stride + base + c];
    d += partial[js * stride + base + 64];
  }
  v /= d;
  float m = v;
  for (int o = 32; o > 0; o >>= 1) m = fmaxf(m, __shfl_xor(m, o, 64));
  float e = __expf(v - m);
  float s = e;
  for (int o = 32; o > 0; o >>= 1) s += __shfl_xor(s, o, 64);
  out[(size_t)r * 64 + c] = e / s;
}

extern "C" void kernel_launch(void* const* d_in, const int* in_sizes, int n_in,
                              void* d_out, int out_size, void* d_ws, size_t ws_size,
                              hipStream_t stream) {
  const float* feat  = (const float*)d_in[0];
  const float* Wgl0  = (const float*)d_in[6];
  const float* bgl0  = (const float*)d_in[7];
  const float* Wgnn0 = (const float*)d_in[8];
  const float* bgnn0 = (const float*)d_in[9];
  const float* Wgl1  = (const float*)d_in[10];
  const float* bgl1  = (const float*)d_in[11];
  const float* Wgnn1 = (const float*)d_in[12];
  const float* bgnn1 = (const float*)d_in[13];
  const float* temp  = (const float*)d_in[14];
  const float* theta = (const float*)d_in[15];
  float* out = (float*)d_out;

  char* ws = (char*)d_ws;
  size_t off = 0;
  auto alloc = [&](size_t bytes) {
    char* p = ws + off;
    off = (off + bytes + 255) & ~(size_t)255;
    return p;
  };
  float*    par0 = (float*)alloc(8ull * NROWS * 144 * 4);  // 37.7 MB
  float*    par1 = par0;  // aliased: par0 is consumed before fused<64> runs
  float*    x1   = (float*)alloc(8192ull * 128 * 4);
  ushort_t* gl0  = (ushort_t*)alloc(8192ull * 128 * 2);
  ushort_t* gl1  = (ushort_t*)alloc(8192ull * 64 * 2);
  ushort_t* h0T  = (ushort_t*)alloc(144ull * 8192 * 2);
  ushort_t* h1T  = (ushort_t*)alloc(80ull * 8192 * 2);
  float*    sq0  = (float*)alloc(8192ull * 4);
  float*    sq1  = (float*)alloc(8192ull * 4);

  lin_kernel<256, 128><<<512, 256, 0, stream>>>(feat, Wgl0, bgl0, Wgnn0, bgnn0, gl0, sq0, h0T);
  fused_kernel<128><<<dim3(128, 8), 256, 0, stream>>>(gl0, sq0, h0T, temp, theta, par0);
  reduce_div_kernel<128, true><<<(8192 * 128) / 256, 256, 0, stream>>>(par0, x1);

  lin_kernel<128, 64><<<512, 256, 0, stream>>>(x1, Wgl1, bgl1, Wgnn1, bgnn1, gl1, sq1, h1T);
  fused_kernel<64><<<dim3(128, 8), 256, 0, stream>>>(gl1, sq1, h1T, temp, theta, par1);
  reduce_softmax_kernel<<<8192, 64, 0, stream>>>(par1, out);
}

// Round 7
// 338.863 us; speedup vs baseline: 1.6785x; 1.5814x over previous
//
#include <hip/hip_runtime.h>
#include <hip/hip_bf16.h>

#define NROWS 8192

typedef __bf16 bf16x8 __attribute__((ext_vector_type(8)));
typedef float f32x4 __attribute__((ext_vector_type(4)));
typedef unsigned short ushort_t;
typedef unsigned int uint_t;

__device__ __forceinline__ ushort_t f2bf(float f) {
  uint_t u = __builtin_bit_cast(uint_t, f);
  u += 0x7fffu + ((u >> 16) & 1u);   // round-to-nearest-even
  return (ushort_t)(u >> 16);
}
__device__ __forceinline__ float bf2f(ushort_t h) {
  uint_t u = ((uint_t)h) << 16;
  return __builtin_bit_cast(float, u);
}

// ---------------------------------------------------------------------------
// lin: computes gl = relu(x@W1+b1), h = x@W2+b2 for a 16-row block, then
// emits FRAGMENT-MAJOR packed outputs (R7: every fused-loop load becomes one
// contiguous 1KB wave burst; kills the 16-segment scatter per load):
//   glf[jt][kk][lane][8]  : lane=(g,q) holds gl[16jt+q][32kk+8g+e]  (A/B frag)
//   hf [jc][P][t2][lane][8]: lane=(g,q) holds h[64jc+32P+8g+e][16t2+q], with
//                            feature==F -> 1.0 (deg ones-column), >F -> 0
//   sq[r] = sum(bf16(gl[r])^2) fp32
// ---------------------------------------------------------------------------
template<int DIN, int F>
__global__ __launch_bounds__(256) void lin_kernel(
    const float* __restrict__ x,
    const float* __restrict__ W1, const float* __restrict__ b1,
    const float* __restrict__ W2, const float* __restrict__ b2,
    ushort_t* __restrict__ glf, float* __restrict__ sq, ushort_t* __restrict__ hf)
{
  constexpr int ROWS = 16;
  constexpr int RP   = 256 / F;      // row phases handled in parallel
  constexpr int RPT  = ROWS / RP;    // rows per thread
  constexpr int Fp   = F + 16;
  constexpr int NT   = Fp / 16;
  constexpr int KK   = F / 32;
  __shared__ float   xs[ROWS][DIN];
  __shared__ float   hs[ROWS][F];
  __shared__ ushort_t gls[ROWS][F];
  __shared__ float   sqs[ROWS];
  const int t  = threadIdx.x;
  const int m  = blockIdx.x;         // 16-row block index
  const int r0 = m * ROWS;

  for (int i = t; i < ROWS * DIN; i += 256)
    xs[i / DIN][i % DIN] = x[(size_t)(r0 + i / DIN) * DIN + (i % DIN)];
  if (t < ROWS) sqs[t] = 0.f;
  __syncthreads();

  const int c = t % F, rr = t / F;
  float a1[RPT], a2[RPT];
  for (int i = 0; i < RPT; ++i) { a1[i] = b1[c]; a2[i] = b2[c]; }
  for (int k = 0; k < DIN; ++k) {
    float w1 = W1[(size_t)k * F + c];
    float w2 = W2[(size_t)k * F + c];
#pragma unroll
    for (int i = 0; i < RPT; ++i) {
      float xv = xs[rr + i * RP][k];
      a1[i] = fmaf(xv, w1, a1[i]);
      a2[i] = fmaf(xv, w2, a2[i]);
    }
  }
#pragma unroll
  for (int i = 0; i < RPT; ++i) {
    int r = rr + i * RP;
    float g = fmaxf(a1[i], 0.f);
    ushort_t gb = f2bf(g);
    gls[r][c] = gb;
    float gf = bf2f(gb);
    atomicAdd(&sqs[r], gf * gf);
    hs[r][c] = a2[i];
  }
  __syncthreads();
  if (t < ROWS) sq[r0 + t] = sqs[t];

  // ---- glf writer: KK*64 chunks of 16B; chunk = (kk, lane); row = lane&15,
  // cols 32kk+8*(lane>>4)..+8 -> contiguous 16B in gls, contiguous 16B out.
  {
    constexpr int CH = KK * 64;
    if (t < CH) {
      int kk = t >> 6, li = t & 63;
      int row = li & 15, c0 = 32 * kk + 8 * (li >> 4);
      uint4 v = *(const uint4*)&gls[row][c0];
      *(uint4*)(glf + ((size_t)(m * KK + kk) * 64 + li) * 8) = v;
    }
  }

  // ---- hf writer: this block's 16 n-rows are lanes g∈{glo,glo+1} of
  // fragment (jc, P); for each t2: value = h[8*(g-glo)+e][16t2+q]
  {
    const int jc  = m >> 2;
    const int P   = (m >> 1) & 1;
    const int glo = (m & 1) * 2;
    for (int idx = t; idx < NT * 32; idx += 256) {
      int t2 = idx >> 5, li = idx & 31;
      int gg = li >> 4, q = li & 15;
      int feat = 16 * t2 + q;
      ushort_t tmp[8];
#pragma unroll
      for (int e = 0; e < 8; ++e) {
        if (feat < F)        tmp[e] = f2bf(hs[8 * gg + e][feat]);
        else if (feat == F)  tmp[e] = (ushort_t)0x3F80;  // bf16(1.0)
        else                 tmp[e] = 0;
      }
      int lane = (glo + gg) * 16 + q;
      uint4* dst = (uint4*)(hf + ((size_t)((jc * 2 + P) * NT + t2) * 64 + lane) * 8);
      *dst = *(const uint4*)tmp;
    }
  }
}

// ---------------------------------------------------------------------------
// fused (R7 = R4 + fragment-major operands): block = 4 waves = one 64-row
// i-tile, each wave privately owns a 16-row strip. Per 64-col j-tile:
// S = gl_i@gl_j^T (MFMA, frags loaded as contiguous 1KB bursts) -> adj =
// sigmoid((1+temp)*dist+5+theta) -> bf16 via swizzled wave-private LDS ->
// acc += adj @ h (hf frags contiguous; ones col = deg). JS=8 j-split across
// blocks; disjoint partial stores, no atomics.
// ---------------------------------------------------------------------------
template<int F>
__global__ __launch_bounds__(256) void fused_kernel(
    const ushort_t* __restrict__ glf, const float* __restrict__ sq,
    const ushort_t* __restrict__ hf,
    const float* __restrict__ temp_p, const float* __restrict__ theta_p,
    float* __restrict__ partial)
{
  constexpr int Fp  = F + 16;
  constexpr int NT  = Fp / 16;    // 9 (F=128) or 5 (F=64)
  constexpr int KK  = F / 32;     // 4 or 2
  constexpr int JS  = 8;
  constexpr int JCH = NROWS / JS; // 1024 j-rows per block
  constexpr float EPS = 1.1920929e-07f;
  __shared__ __align__(16) ushort_t adjlds[64 * 64];  // 8 KB, XOR-swizzled

  const int w = threadIdx.x >> 6, lane = threadIdx.x & 63;
  const int g = lane >> 4, q = lane & 15;
  const int irow  = blockIdx.x * 64 + 16 * w;   // this wave's private 16 rows
  const int jbase = blockIdx.y * JCH;
  const float c1 = 1.0f + *temp_p;
  const float c0 = 5.0f + *theta_p;

  // hoist A-fragments (gl_i rows; fragment-major -> contiguous) and sq_i
  bf16x8 aF[KK];
#pragma unroll
  for (int kk = 0; kk < KK; ++kk)
    aF[kk] = *(const bf16x8*)(glf + ((size_t)((irow >> 4) * KK + kk) * 64 + lane) * 8);
  float sqi[4];
#pragma unroll
  for (int r = 0; r < 4; ++r) sqi[r] = sq[irow + 4 * g + r];

  f32x4 acc[NT];
#pragma unroll
  for (int i = 0; i < NT; ++i) acc[i] = (f32x4){0.f, 0.f, 0.f, 0.f};

#pragma unroll 1
  for (int j0 = jbase; j0 < jbase + JCH; j0 += 64) {
    // ---- phase A: S tile [16][64]; B-frags are contiguous 1KB bursts
    f32x4 s[4];
    float sqj[4];
#pragma unroll
    for (int tt = 0; tt < 4; ++tt) {
      sqj[tt] = sq[j0 + 16 * tt + q];
      f32x4 cacc = (f32x4){0.f, 0.f, 0.f, 0.f};
#pragma unroll
      for (int kk = 0; kk < KK; ++kk) {
        bf16x8 b = *(const bf16x8*)(glf + ((size_t)(((j0 >> 4) + tt) * KK + kk) * 64 + lane) * 8);
        cacc = __builtin_amdgcn_mfma_f32_16x16x32_bf16(aF[kk], b, cacc, 0, 0, 0);
      }
      s[tt] = cacc;
    }
    // ---- elementwise: diff -> dist -> sigmoid -> bf16 adj into LDS
#pragma unroll
    for (int tt = 0; tt < 4; ++tt) {
#pragma unroll
      for (int r = 0; r < 4; ++r) {
        float diff = fmaxf(sqi[r] + sqj[tt] - 2.f * s[tt][r], 0.f);
        float arg = c0;
        if (diff != 0.f) arg = c0 - c1 * __builtin_amdgcn_sqrtf(diff + EPS);
        float adjv = __builtin_amdgcn_rcpf(1.f + __expf(-arg));
        int row = 16 * w + 4 * g + r;
        int col = 16 * tt + q;
        int byte = row * 128 + ((col * 2) ^ ((row & 7) << 4));
        *(ushort_t*)((char*)adjlds + byte) = f2bf(adjv);
      }
    }
    // RAW fence (cross-lane, same wave): writes visible before reads.
    asm volatile("s_waitcnt lgkmcnt(0)" ::: "memory");
    // ---- phase B: acc += adj[16][64] @ h[64][Fp]; hf frags contiguous
#pragma unroll
    for (int kk2 = 0; kk2 < 2; ++kk2) {
      int row = 16 * w + q;
      int byte = row * 128 + ((64 * kk2 + 16 * g) ^ ((row & 7) << 4));
      bf16x8 aP = *(const bf16x8*)((char*)adjlds + byte);
#pragma unroll
      for (int t2 = 0; t2 < NT; ++t2) {
        bf16x8 hF = *(const bf16x8*)(hf + ((size_t)(((j0 >> 6) * 2 + kk2) * NT + t2) * 64 + lane) * 8);
        acc[t2] = __builtin_amdgcn_mfma_f32_16x16x32_bf16(aP, hF, acc[t2], 0, 0, 0);
      }
    }
    // WAR fence: this iter's ds_reads done before next iter's ds_writes.
    asm volatile("s_waitcnt lgkmcnt(0)" ::: "memory");
  }

  // ---- epilogue: each wave owns rows irow..irow+15 -> direct disjoint store
  float* op = partial + ((size_t)blockIdx.y * NROWS + irow) * Fp;
#pragma unroll
  for (int t2 = 0; t2 < NT; ++t2)
#pragma unroll
    for (int r = 0; r < 4; ++r)
      op[(size_t)(4 * g + r) * Fp + 16 * t2 + q] = acc[t2][r];
}

// x_next = relu(sum_js(partial col c) / sum_js(partial col F))
template<int F, bool RELU>
__global__ __launch_bounds__(256) void reduce_div_kernel(
    const float* __restrict__ partial, float* __restrict__ out)
{
  int idx = blockIdx.x * 256 + threadIdx.x;
  int r = idx / F, c = idx % F;
  size_t base = (size_t)r * (F + 16);
  size_t stride = (size_t)NROWS * (F + 16);
  float s = 0.f, d = 0.f;
#pragma unroll
  for (int js = 0; js < 8; ++js) {
    s += partial[js * stride + base + c];
    d += partial[js * stride + base + F];
  }
  float v = s / d;
  if (RELU) v = fmaxf(v, 0.f);
  out[idx] = v;
}

// out = softmax(sum_js(partial)/deg) rowwise; one wave per row
__global__ __launch_bounds__(64) void reduce_softmax_kernel(
    const float* __restrict__ partial, float* __restrict__ out)
{
  int r = blockIdx.x, c = threadIdx.x;
  size_t base = (size_t)r * 80;
  size_t stride = (size_t)NROWS * 80;
  float v = 0.f, d = 0.f;
#pragma unroll
  for (int js = 0; js < 8; ++js) {
    v += partial[js * stride + base + c];
    d += partial[js * stride + base + 64];
  }
  v /= d;
  float m = v;
  for (int o = 32; o > 0; o >>= 1) m = fmaxf(m, __shfl_xor(m, o, 64));
  float e = __expf(v - m);
  float s = e;
  for (int o = 32; o > 0; o >>= 1) s += __shfl_xor(s, o, 64);
  out[(size_t)r * 64 + c] = e / s;
}

extern "C" void kernel_launch(void* const* d_in, const int* in_sizes, int n_in,
                              void* d_out, int out_size, void* d_ws, size_t ws_size,
                              hipStream_t stream) {
  const float* feat  = (const float*)d_in[0];
  const float* Wgl0  = (const float*)d_in[6];
  const float* bgl0  = (const float*)d_in[7];
  const float* Wgnn0 = (const float*)d_in[8];
  const float* bgnn0 = (const float*)d_in[9];
  const float* Wgl1  = (const float*)d_in[10];
  const float* bgl1  = (const float*)d_in[11];
  const float* Wgnn1 = (const float*)d_in[12];
  const float* bgnn1 = (const float*)d_in[13];
  const float* temp  = (const float*)d_in[14];
  const float* theta = (const float*)d_in[15];
  float* out = (float*)d_out;

  char* ws = (char*)d_ws;
  size_t off = 0;
  auto alloc = [&](size_t bytes) {
    char* p = ws + off;
    off = (off + bytes + 255) & ~(size_t)255;
    return p;
  };
  float*    par0 = (float*)alloc(8ull * NROWS * 144 * 4);  // 37.7 MB
  float*    par1 = par0;  // aliased: par0 is consumed before fused<64> runs
  float*    x1   = (float*)alloc(8192ull * 128 * 4);
  ushort_t* glf0 = (ushort_t*)alloc((8192ull / 16) * 4 * 64 * 8 * 2);  // 2 MB
  ushort_t* glf1 = (ushort_t*)alloc((8192ull / 16) * 2 * 64 * 8 * 2);  // 1 MB
  ushort_t* hf0  = (ushort_t*)alloc((8192ull / 64) * 2 * 9 * 64 * 8 * 2);  // 2.25 MB
  ushort_t* hf1  = (ushort_t*)alloc((8192ull / 64) * 2 * 5 * 64 * 8 * 2);  // 1.25 MB
  float*    sq0  = (float*)alloc(8192ull * 4);
  float*    sq1  = (float*)alloc(8192ull * 4);

  lin_kernel<256, 128><<<512, 256, 0, stream>>>(feat, Wgl0, bgl0, Wgnn0, bgnn0, glf0, sq0, hf0);
  fused_kernel<128><<<dim3(128, 8), 256, 0, stream>>>(glf0, sq0, hf0, temp, theta, par0);
  reduce_div_kernel<128, true><<<(8192 * 128) / 256, 256, 0, stream>>>(par0, x1);

  lin_kernel<128, 64><<<512, 256, 0, stream>>>(x1, Wgl1, bgl1, Wgnn1, bgnn1, glf1, sq1, hf1);
  fused_kernel<64><<<dim3(128, 8), 256, 0, stream>>>(glf1, sq1, hf1, temp, theta, par1);
  reduce_softmax_kernel<<<8192, 64, 0, stream>>>(par1, out);
}

// Round 8
// 237.766 us; speedup vs baseline: 2.3921x; 1.4252x over previous
//
#include <hip/hip_runtime.h>
#include <hip/hip_bf16.h>

#define NROWS 8192

typedef __bf16 bf16x8 __attribute__((ext_vector_type(8)));
typedef float f32x4 __attribute__((ext_vector_type(4)));
typedef unsigned short ushort_t;
typedef unsigned int uint_t;

__device__ __forceinline__ ushort_t f2bf(float f) {
  uint_t u = __builtin_bit_cast(uint_t, f);
  u += 0x7fffu + ((u >> 16) & 1u);   // round-to-nearest-even
  return (ushort_t)(u >> 16);
}
__device__ __forceinline__ float bf2f(ushort_t h) {
  uint_t u = ((uint_t)h) << 16;
  return __builtin_bit_cast(float, u);
}
// async global->LDS DMA, 16B per lane; LDS dest = uniform base + lane*16
__device__ __forceinline__ void load_lds16(const ushort_t* g, ushort_t* l) {
  __builtin_amdgcn_global_load_lds(
      (const __attribute__((address_space(1))) unsigned int*)g,
      (__attribute__((address_space(3))) unsigned int*)l, 16, 0, 0);
}

// ---------------------------------------------------------------------------
// lin: computes gl = relu(x@W1+b1), h = x@W2+b2 for a 16-row block, then
// emits FRAGMENT-MAJOR packed outputs (R7):
//   glf[jt][kk][lane][8]  : lane=(g,q) holds gl[16jt+q][32kk+8g+e]  (A/B frag)
//   hf [jc][P][t2][lane][8]: lane=(g,q) holds h[64jc+32P+8g+e][16t2+q], with
//                            feature==F -> 1.0 (deg ones-column), >F -> 0
//   sq[r] = sum(bf16(gl[r])^2) fp32
// ---------------------------------------------------------------------------
template<int DIN, int F>
__global__ __launch_bounds__(256) void lin_kernel(
    const float* __restrict__ x,
    const float* __restrict__ W1, const float* __restrict__ b1,
    const float* __restrict__ W2, const float* __restrict__ b2,
    ushort_t* __restrict__ glf, float* __restrict__ sq, ushort_t* __restrict__ hf)
{
  constexpr int ROWS = 16;
  constexpr int RP   = 256 / F;      // row phases handled in parallel
  constexpr int RPT  = ROWS / RP;    // rows per thread
  constexpr int Fp   = F + 16;
  constexpr int NT   = Fp / 16;
  constexpr int KK   = F / 32;
  __shared__ float   xs[ROWS][DIN];
  __shared__ float   hs[ROWS][F];
  __shared__ ushort_t gls[ROWS][F];
  __shared__ float   sqs[ROWS];
  const int t  = threadIdx.x;
  const int m  = blockIdx.x;         // 16-row block index
  const int r0 = m * ROWS;

  for (int i = t; i < ROWS * DIN; i += 256)
    xs[i / DIN][i % DIN] = x[(size_t)(r0 + i / DIN) * DIN + (i % DIN)];
  if (t < ROWS) sqs[t] = 0.f;
  __syncthreads();

  const int c = t % F, rr = t / F;
  float a1[RPT], a2[RPT];
  for (int i = 0; i < RPT; ++i) { a1[i] = b1[c]; a2[i] = b2[c]; }
  for (int k = 0; k < DIN; ++k) {
    float w1 = W1[(size_t)k * F + c];
    float w2 = W2[(size_t)k * F + c];
#pragma unroll
    for (int i = 0; i < RPT; ++i) {
      float xv = xs[rr + i * RP][k];
      a1[i] = fmaf(xv, w1, a1[i]);
      a2[i] = fmaf(xv, w2, a2[i]);
    }
  }
#pragma unroll
  for (int i = 0; i < RPT; ++i) {
    int r = rr + i * RP;
    float g = fmaxf(a1[i], 0.f);
    ushort_t gb = f2bf(g);
    gls[r][c] = gb;
    float gf = bf2f(gb);
    atomicAdd(&sqs[r], gf * gf);
    hs[r][c] = a2[i];
  }
  __syncthreads();
  if (t < ROWS) sq[r0 + t] = sqs[t];

  // ---- glf writer: chunk = (kk, lane); row = lane&15, cols 32kk+8g..+8
  {
    constexpr int CH = KK * 64;
    if (t < CH) {
      int kk = t >> 6, li = t & 63;
      int row = li & 15, c0 = 32 * kk + 8 * (li >> 4);
      uint4 v = *(const uint4*)&gls[row][c0];
      *(uint4*)(glf + ((size_t)(m * KK + kk) * 64 + li) * 8) = v;
    }
  }

  // ---- hf writer: block's 16 n-rows are lanes g∈{glo,glo+1} of frag (jc,P)
  {
    const int jc  = m >> 2;
    const int P   = (m >> 1) & 1;
    const int glo = (m & 1) * 2;
    for (int idx = t; idx < NT * 32; idx += 256) {
      int t2 = idx >> 5, li = idx & 31;
      int gg = li >> 4, q = li & 15;
      int feat = 16 * t2 + q;
      ushort_t tmp[8];
#pragma unroll
      for (int e = 0; e < 8; ++e) {
        if (feat < F)        tmp[e] = f2bf(hs[8 * gg + e][feat]);
        else if (feat == F)  tmp[e] = (ushort_t)0x3F80;  // bf16(1.0)
        else                 tmp[e] = 0;
      }
      int lane = (glo + gg) * 16 + q;
      uint4* dst = (uint4*)(hf + ((size_t)((jc * 2 + P) * NT + t2) * 64 + lane) * 8);
      *dst = *(const uint4*)tmp;
    }
  }
}

// ---------------------------------------------------------------------------
// fused (R8 = R7 + LDS staging of shared j-side operands): per j-tile the
// block DMAs B-frags (4*KK KB) + hf-frags (2*NT KB) into LDS ONCE via
// global_load_lds (contiguous fragment-major source, linear LDS dest), then
// all 4 waves ds_read_b128 their fragments. Kills the 4x per-wave redundant
// global loads that R7 left as the bottleneck. m97-style 2-barrier loop.
// Wave-private adj roundtrip + JS=8 disjoint partials unchanged.
// ---------------------------------------------------------------------------
template<int F>
__global__ __launch_bounds__(256) void fused_kernel(
    const ushort_t* __restrict__ glf, const float* __restrict__ sq,
    const ushort_t* __restrict__ hf,
    const float* __restrict__ temp_p, const float* __restrict__ theta_p,
    float* __restrict__ partial)
{
  constexpr int Fp  = F + 16;
  constexpr int NT  = Fp / 16;    // 9 (F=128) or 5 (F=64)
  constexpr int KK  = F / 32;     // 4 or 2
  constexpr int JS  = 8;
  constexpr int JCH = NROWS / JS; // 1024 j-rows per block
  constexpr int NCHB = 4 * KK;        // B-frag 1KB chunks per j-tile
  constexpr int NCH  = NCHB + 2 * NT; // + hf chunks
  constexpr float EPS = 1.1920929e-07f;
  __shared__ __align__(16) ushort_t stage[NCH * 512];  // 34KB (F=128) staged
  __shared__ __align__(16) ushort_t adjlds[64 * 64];   // 8KB, XOR-swizzled

  const int w = threadIdx.x >> 6, lane = threadIdx.x & 63;
  const int g = lane >> 4, q = lane & 15;
  const int irow  = blockIdx.x * 64 + 16 * w;   // this wave's private 16 rows
  const int jbase = blockIdx.y * JCH;
  const float c1 = 1.0f + *temp_p;
  const float c0 = 5.0f + *theta_p;

  // hoist A-fragments (gl_i rows; fragment-major -> contiguous) and sq_i
  bf16x8 aF[KK];
#pragma unroll
  for (int kk = 0; kk < KK; ++kk)
    aF[kk] = *(const bf16x8*)(glf + ((size_t)((irow >> 4) * KK + kk) * 64 + lane) * 8);
  float sqi[4];
#pragma unroll
  for (int r = 0; r < 4; ++r) sqi[r] = sq[irow + 4 * g + r];

  f32x4 acc[NT];
#pragma unroll
  for (int i = 0; i < NT; ++i) acc[i] = (f32x4){0.f, 0.f, 0.f, 0.f};

#pragma unroll 1
  for (int j0 = jbase; j0 < jbase + JCH; j0 += 64) {
    // WAR: previous iteration's LDS reads complete before restaging
    __syncthreads();
    // ---- stage: two contiguous regions -> linear LDS, 16B/lane DMA
    {
      const ushort_t* glB = glf + (size_t)(j0 >> 4) * KK * 512;
      const ushort_t* glH = hf  + (size_t)(j0 >> 6) * 2 * NT * 512;
      for (int ch = w; ch < NCH; ch += 4) {
        const ushort_t* src = (ch < NCHB) ? (glB + (size_t)ch * 512)
                                          : (glH + (size_t)(ch - NCHB) * 512);
        load_lds16(src + lane * 8, stage + ch * 512);
      }
    }
    __syncthreads();  // drains vmcnt (global_load_lds) + barrier

    // ---- phase A: S tile [16][64]; B-frags from LDS (base+imm, no conflicts)
    f32x4 s[4];
    float sqj[4];
#pragma unroll
    for (int tt = 0; tt < 4; ++tt) {
      sqj[tt] = sq[j0 + 16 * tt + q];
      f32x4 cacc = (f32x4){0.f, 0.f, 0.f, 0.f};
#pragma unroll
      for (int kk = 0; kk < KK; ++kk) {
        bf16x8 b = *(const bf16x8*)(stage + (tt * KK + kk) * 512 + lane * 8);
        cacc = __builtin_amdgcn_mfma_f32_16x16x32_bf16(aF[kk], b, cacc, 0, 0, 0);
      }
      s[tt] = cacc;
    }
    // ---- elementwise: diff -> dist -> sigmoid -> bf16 adj into private LDS
#pragma unroll
    for (int tt = 0; tt < 4; ++tt) {
#pragma unroll
      for (int r = 0; r < 4; ++r) {
        float diff = fmaxf(sqi[r] + sqj[tt] - 2.f * s[tt][r], 0.f);
        float arg = c0;
        if (diff != 0.f) arg = c0 - c1 * __builtin_amdgcn_sqrtf(diff + EPS);
        float adjv = __builtin_amdgcn_rcpf(1.f + __expf(-arg));
        int row = 16 * w + 4 * g + r;
        int col = 16 * tt + q;
        int byte = row * 128 + ((col * 2) ^ ((row & 7) << 4));
        *(ushort_t*)((char*)adjlds + byte) = f2bf(adjv);
      }
    }
    // RAW fence (cross-lane, same wave)
    asm volatile("s_waitcnt lgkmcnt(0)" ::: "memory");
    // ---- phase B: acc += adj[16][64] @ h[64][Fp]; hf frags from LDS
#pragma unroll
    for (int kk2 = 0; kk2 < 2; ++kk2) {
      int row = 16 * w + q;
      int byte = row * 128 + ((64 * kk2 + 16 * g) ^ ((row & 7) << 4));
      bf16x8 aP = *(const bf16x8*)((char*)adjlds + byte);
#pragma unroll
      for (int t2 = 0; t2 < NT; ++t2) {
        bf16x8 hF = *(const bf16x8*)(stage + (NCHB + kk2 * NT + t2) * 512 + lane * 8);
        acc[t2] = __builtin_amdgcn_mfma_f32_16x16x32_bf16(aP, hF, acc[t2], 0, 0, 0);
      }
    }
    // WAR fence for adj buffer (next iter rewrites it)
    asm volatile("s_waitcnt lgkmcnt(0)" ::: "memory");
  }

  // ---- epilogue: each wave owns rows irow..irow+15 -> direct disjoint store
  float* op = partial + ((size_t)blockIdx.y * NROWS + irow) * Fp;
#pragma unroll
  for (int t2 = 0; t2 < NT; ++t2)
#pragma unroll
    for (int r = 0; r < 4; ++r)
      op[(size_t)(4 * g + r) * Fp + 16 * t2 + q] = acc[t2][r];
}

// x_next = relu(sum_js(partial col c) / sum_js(partial col F))
template<int F, bool RELU>
__global__ __launch_bounds__(256) void reduce_div_kernel(
    const float* __restrict__ partial, float* __restrict__ out)
{
  int idx = blockIdx.x * 256 + threadIdx.x;
  int r = idx / F, c = idx % F;
  size_t base = (size_t)r * (F + 16);
  size_t stride = (size_t)NROWS * (F + 16);
  float s = 0.f, d = 0.f;
#pragma unroll
  for (int js = 0; js < 8; ++js) {
    s += partial[js * stride + base + c];
    d += partial[js * stride + base + F];
  }
  float v = s / d;
  if (RELU) v = fmaxf(v, 0.f);
  out[idx] = v;
}

// out = softmax(sum_js(partial)/deg) rowwise; one wave per row
__global__ __launch_bounds__(64) void reduce_softmax_kernel(
    const float* __restrict__ partial, float* __restrict__ out)
{
  int r = blockIdx.x, c = threadIdx.x;
  size_t base = (size_t)r * 80;
  size_t stride = (size_t)NROWS * 80;
  float v = 0.f, d = 0.f;
#pragma unroll
  for (int js = 0; js < 8; ++js) {
    v += partial[js * stride + base + c];
    d += partial[js * stride + base + 64];
  }
  v /= d;
  float m = v;
  for (int o = 32; o > 0; o >>= 1) m = fmaxf(m, __shfl_xor(m, o, 64));
  float e = __expf(v - m);
  float s = e;
  for (int o = 32; o > 0; o >>= 1) s += __shfl_xor(s, o, 64);
  out[(size_t)r * 64 + c] = e / s;
}

extern "C" void kernel_launch(void* const* d_in, const int* in_sizes, int n_in,
                              void* d_out, int out_size, void* d_ws, size_t ws_size,
                              hipStream_t stream) {
  const float* feat  = (const float*)d_in[0];
  const float* Wgl0  = (const float*)d_in[6];
  const float* bgl0  = (const float*)d_in[7];
  const float* Wgnn0 = (const float*)d_in[8];
  const float* bgnn0 = (const float*)d_in[9];
  const float* Wgl1  = (const float*)d_in[10];
  const float* bgl1  = (const float*)d_in[11];
  const float* Wgnn1 = (const float*)d_in[12];
  const float* bgnn1 = (const float*)d_in[13];
  const float* temp  = (const float*)d_in[14];
  const float* theta = (const float*)d_in[15];
  float* out = (float*)d_out;

  char* ws = (char*)d_ws;
  size_t off = 0;
  auto alloc = [&](size_t bytes) {
    char* p = ws + off;
    off = (off + bytes + 255) & ~(size_t)255;
    return p;
  };
  float*    par0 = (float*)alloc(8ull * NROWS * 144 * 4);  // 37.7 MB
  float*    par1 = par0;  // aliased: par0 is consumed before fused<64> runs
  float*    x1   = (float*)alloc(8192ull * 128 * 4);
  ushort_t* glf0 = (ushort_t*)alloc((8192ull / 16) * 4 * 64 * 8 * 2);  // 2 MB
  ushort_t* glf1 = (ushort_t*)alloc((8192ull / 16) * 2 * 64 * 8 * 2);  // 1 MB
  ushort_t* hf0  = (ushort_t*)alloc((8192ull / 64) * 2 * 9 * 64 * 8 * 2);  // 2.25 MB
  ushort_t* hf1  = (ushort_t*)alloc((8192ull / 64) * 2 * 5 * 64 * 8 * 2);  // 1.25 MB
  float*    sq0  = (float*)alloc(8192ull * 4);
  float*    sq1  = (float*)alloc(8192ull * 4);

  lin_kernel<256, 128><<<512, 256, 0, stream>>>(feat, Wgl0, bgl0, Wgnn0, bgnn0, glf0, sq0, hf0);
  fused_kernel<128><<<dim3(128, 8), 256, 0, stream>>>(glf0, sq0, hf0, temp, theta, par0);
  reduce_div_kernel<128, true><<<(8192 * 128) / 256, 256, 0, stream>>>(par0, x1);

  lin_kernel<128, 64><<<512, 256, 0, stream>>>(x1, Wgl1, bgl1, Wgnn1, bgnn1, glf1, sq1, hf1);
  fused_kernel<64><<<dim3(128, 8), 256, 0, stream>>>(glf1, sq1, hf1, temp, theta, par1);
  reduce_softmax_kernel<<<8192, 64, 0, stream>>>(par1, out);
}